// Round 1
// baseline (618.172 us; speedup 1.0000x reference)
//
#include <hip/hip_runtime.h>
#include <math.h>

#define BB 8
#define NN 1024
#define DIM 768
#define HEADS 12
#define CR 384
#define HD 32
#define MROWS (BB*NN)   // 8192
#define EPS 1e-5f

// ---------------- row stats: mean + rsqrt(var+eps) per row ----------------
__global__ __launch_bounds__(256) void row_stats(const float* __restrict__ A, int K,
                                                 float* __restrict__ mu, float* __restrict__ rs) {
    int row = blockIdx.x;
    const float* a = A + (size_t)row * K;
    float s = 0.f, ss = 0.f;
    for (int k = threadIdx.x; k < K; k += 256) {
        float v = a[k];
        s += v; ss += v * v;
    }
    for (int off = 32; off; off >>= 1) {
        s  += __shfl_down(s, off, 64);
        ss += __shfl_down(ss, off, 64);
    }
    __shared__ float redS[4], redSS[4];
    int lane = threadIdx.x & 63, wv = threadIdx.x >> 6;
    if (lane == 0) { redS[wv] = s; redSS[wv] = ss; }
    __syncthreads();
    if (threadIdx.x == 0) {
        float S = redS[0] + redS[1] + redS[2] + redS[3];
        float SS = redSS[0] + redSS[1] + redSS[2] + redSS[3];
        float m = S / K;
        float var = SS / K - m * m;
        mu[row] = m;
        rs[row] = rsqrtf(var + EPS);
    }
}

// ------------- C[m][n] = sum_k ((A[m][k]-mu[m])*rs[m]*g[k]+bt[k]) * W[n][k] + bias[n] -------------
// 64x64 tile, 256 threads, 4x4 microtile, K-step 16, A/W staged k-major in LDS.
__global__ __launch_bounds__(256) void gemm_ln(
    const float* __restrict__ A, int K, int Nn,
    const float* __restrict__ mu, const float* __restrict__ rs,
    const float* __restrict__ g, const float* __restrict__ bt,
    const float* __restrict__ W, const float* __restrict__ bias,
    float* __restrict__ C)
{
    const int m0 = blockIdx.y * 64;
    const int n0 = blockIdx.x * 64;
    __shared__ float As[16][68];   // [k][m], stride 68 -> 16B-aligned float4 rows
    __shared__ float Bs[16][68];   // [k][n]
    const int t = threadIdx.x;
    const int tx = t & 15, ty = t >> 4;
    const int lm = t >> 2;            // 0..63 : tile row this thread stages
    const int kq = (t & 3) * 4;       // 0,4,8,12 : k quad
    float acc[4][4] = {};
    const float lmu = mu[m0 + lm], lrs = rs[m0 + lm];
    const float* arow = A + (size_t)(m0 + lm) * K;
    const float* wrow = W + (size_t)(n0 + lm) * K;
    for (int k0 = 0; k0 < K; k0 += 16) {
        float4 av = *(const float4*)(arow + k0 + kq);
        float4 wv = *(const float4*)(wrow + k0 + kq);
        float4 gv = *(const float4*)(g + k0 + kq);
        float4 bv = *(const float4*)(bt + k0 + kq);
        As[kq + 0][lm] = (av.x - lmu) * lrs * gv.x + bv.x;
        As[kq + 1][lm] = (av.y - lmu) * lrs * gv.y + bv.y;
        As[kq + 2][lm] = (av.z - lmu) * lrs * gv.z + bv.z;
        As[kq + 3][lm] = (av.w - lmu) * lrs * gv.w + bv.w;
        Bs[kq + 0][lm] = wv.x;
        Bs[kq + 1][lm] = wv.y;
        Bs[kq + 2][lm] = wv.z;
        Bs[kq + 3][lm] = wv.w;
        __syncthreads();
#pragma unroll
        for (int kk = 0; kk < 16; kk++) {
            float4 a4 = *(const float4*)&As[kk][ty * 4];
            float4 b4 = *(const float4*)&Bs[kk][tx * 4];
            float av4[4] = {a4.x, a4.y, a4.z, a4.w};
            float bv4[4] = {b4.x, b4.y, b4.z, b4.w};
#pragma unroll
            for (int i = 0; i < 4; i++)
#pragma unroll
                for (int j = 0; j < 4; j++)
                    acc[i][j] += av4[i] * bv4[j];
        }
        __syncthreads();
    }
    float4 biasv = make_float4(0.f, 0.f, 0.f, 0.f);
    if (bias) biasv = *(const float4*)(bias + n0 + tx * 4);
#pragma unroll
    for (int i = 0; i < 4; i++) {
        int row = m0 + ty * 4 + i;
        float4 o;
        o.x = acc[i][0] + biasv.x;
        o.y = acc[i][1] + biasv.y;
        o.z = acc[i][2] + biasv.z;
        o.w = acc[i][3] + biasv.w;
        *(float4*)(C + (size_t)row * Nn + n0 + tx * 4) = o;
    }
}

// ---------------- flash attention per (b,head,64-query tile) + residual add ----------------
__global__ __launch_bounds__(256) void attn_kernel(
    const float* __restrict__ q, const float* __restrict__ k, const float* __restrict__ v,
    const float* __restrict__ h, float* __restrict__ out)
{
    const int qt = blockIdx.x;           // 0..15
    const int bh = blockIdx.y;           // 0..95
    const int b = bh / HEADS, head = bh % HEADS;
    const int hc = head * HD;
    __shared__ float Qs[64][33];
    __shared__ float Ks[64][33];
    __shared__ float Vs[64][36];         // stride 36: float4-aligned rows
    __shared__ float Ss[64][65];
    __shared__ float red[64][5];
    const int t = threadIdx.x;
    const int tx = t & 15, ty = t >> 4;  // S-compute mapping
    const int r = t >> 2;                // softmax/PV row ownership (0..63)
    const int cs = t & 3;                // column segment
    const float scale = 0.17677669529663687f;  // 1/sqrt(32)

    for (int i = t; i < 512; i += 256) {
        int rr = i >> 3, c4 = (i & 7) * 4;
        float4 qv = *(const float4*)(q + (size_t)(b * NN + qt * 64 + rr) * CR + hc + c4);
        Qs[rr][c4 + 0] = qv.x * scale;
        Qs[rr][c4 + 1] = qv.y * scale;
        Qs[rr][c4 + 2] = qv.z * scale;
        Qs[rr][c4 + 3] = qv.w * scale;
    }
    float accO[8] = {0.f, 0.f, 0.f, 0.f, 0.f, 0.f, 0.f, 0.f};
    float m_r = -INFINITY, l_r = 0.f;
    __syncthreads();

    for (int kt = 0; kt < 16; kt++) {
        for (int i = t; i < 512; i += 256) {
            int rr = i >> 3, c4 = (i & 7) * 4;
            float4 kv = *(const float4*)(k + (size_t)(b * NN + kt * 64 + rr) * CR + hc + c4);
            float4 vv = *(const float4*)(v + (size_t)(b * NN + kt * 64 + rr) * CR + hc + c4);
            Ks[rr][c4 + 0] = kv.x; Ks[rr][c4 + 1] = kv.y;
            Ks[rr][c4 + 2] = kv.z; Ks[rr][c4 + 3] = kv.w;
            Vs[rr][c4 + 0] = vv.x; Vs[rr][c4 + 1] = vv.y;
            Vs[rr][c4 + 2] = vv.z; Vs[rr][c4 + 3] = vv.w;
        }
        __syncthreads();
        // S tile = Qs @ Ks^T
        float s[4][4] = {};
#pragma unroll 8
        for (int kk = 0; kk < 32; kk++) {
            float a0 = Qs[ty * 4 + 0][kk], a1 = Qs[ty * 4 + 1][kk];
            float a2 = Qs[ty * 4 + 2][kk], a3 = Qs[ty * 4 + 3][kk];
            float b0 = Ks[tx * 4 + 0][kk], b1 = Ks[tx * 4 + 1][kk];
            float b2 = Ks[tx * 4 + 2][kk], b3 = Ks[tx * 4 + 3][kk];
            s[0][0] += a0 * b0; s[0][1] += a0 * b1; s[0][2] += a0 * b2; s[0][3] += a0 * b3;
            s[1][0] += a1 * b0; s[1][1] += a1 * b1; s[1][2] += a1 * b2; s[1][3] += a1 * b3;
            s[2][0] += a2 * b0; s[2][1] += a2 * b1; s[2][2] += a2 * b2; s[2][3] += a2 * b3;
            s[3][0] += a3 * b0; s[3][1] += a3 * b1; s[3][2] += a3 * b2; s[3][3] += a3 * b3;
        }
#pragma unroll
        for (int i = 0; i < 4; i++)
#pragma unroll
            for (int j = 0; j < 4; j++)
                Ss[ty * 4 + i][tx * 4 + j] = s[i][j];
        __syncthreads();
        // online softmax: row r, col segment cs (16 cols)
        float lmax = -INFINITY;
#pragma unroll
        for (int j = 0; j < 16; j++) lmax = fmaxf(lmax, Ss[r][cs * 16 + j]);
        red[r][cs] = lmax;
        __syncthreads();
        float m_new = fmaxf(m_r, fmaxf(fmaxf(red[r][0], red[r][1]), fmaxf(red[r][2], red[r][3])));
        float alpha = __expf(m_r - m_new);   // m_r = -inf initially -> alpha = 0
        float lsum = 0.f;
#pragma unroll
        for (int j = 0; j < 16; j++) {
            float e = __expf(Ss[r][cs * 16 + j] - m_new);
            Ss[r][cs * 16 + j] = e;
            lsum += e;
        }
        __syncthreads();                     // red max-reads done; Ss fully exp'd
        red[r][cs] = lsum;
        __syncthreads();
        l_r = l_r * alpha + (red[r][0] + red[r][1] + red[r][2] + red[r][3]);
        m_r = m_new;
#pragma unroll
        for (int i = 0; i < 8; i++) accO[i] *= alpha;
        // PV accumulate: this thread owns row r, dims d0..d0+7
        const int d0 = cs * 8;
#pragma unroll 4
        for (int j = 0; j < 64; j++) {
            float p = Ss[r][j];
            float4 v0 = *(const float4*)&Vs[j][d0];
            float4 v1 = *(const float4*)&Vs[j][d0 + 4];
            accO[0] += p * v0.x; accO[1] += p * v0.y; accO[2] += p * v0.z; accO[3] += p * v0.w;
            accO[4] += p * v1.x; accO[5] += p * v1.y; accO[6] += p * v1.z; accO[7] += p * v1.w;
        }
        __syncthreads();                     // protect Ks/Vs/Ss for next tile
    }
    const float inv = 1.f / l_r;
    const int d0 = cs * 8;
    const size_t row = (size_t)(b * NN + qt * 64 + r);
    const float* hp = h + row * CR + hc + d0;
    float* op = out + row * CR + hc + d0;
#pragma unroll
    for (int i = 0; i < 8; i++) op[i] = hp[i] + accO[i] * inv;
}

extern "C" void kernel_launch(void* const* d_in, const int* in_sizes, int n_in,
                              void* d_out, int out_size, void* d_ws, size_t ws_size,
                              hipStream_t stream) {
    const float* x      = (const float*)d_in[0];
    const float* ln0_g  = (const float*)d_in[1];
    const float* ln0_b  = (const float*)d_in[2];
    const float* w_proj = (const float*)d_in[3];
    const float* b_proj = (const float*)d_in[4];
    const float* ln1_g  = (const float*)d_in[5];
    const float* ln1_b  = (const float*)d_in[6];
    const float* wq     = (const float*)d_in[7];
    const float* wk     = (const float*)d_in[8];
    const float* wv     = (const float*)d_in[9];
    float* out = (float*)d_out;

    float* ws  = (float*)d_ws;
    float* mu0 = ws;
    float* rs0 = ws + 8192;
    float* mu1 = ws + 16384;
    float* rs1 = ws + 24576;
    float* hbuf = ws + 32768;                 // 8192*384
    float* qbuf = hbuf + (size_t)MROWS * CR;
    float* kbuf = qbuf + (size_t)MROWS * CR;
    float* vbuf = kbuf + (size_t)MROWS * CR;

    // 1. LN0 stats
    row_stats<<<MROWS, 256, 0, stream>>>(x, DIM, mu0, rs0);
    // 2. h = LN0(x) @ w_proj^T + b_proj
    gemm_ln<<<dim3(CR / 64, MROWS / 64), 256, 0, stream>>>(
        x, DIM, CR, mu0, rs0, ln0_g, ln0_b, w_proj, b_proj, hbuf);
    // 3. LN1 stats
    row_stats<<<MROWS, 256, 0, stream>>>(hbuf, CR, mu1, rs1);
    // 4-6. q,k,v = LN1(h) @ w{q,k,v}^T
    gemm_ln<<<dim3(CR / 64, MROWS / 64), 256, 0, stream>>>(
        hbuf, CR, CR, mu1, rs1, ln1_g, ln1_b, wq, nullptr, qbuf);
    gemm_ln<<<dim3(CR / 64, MROWS / 64), 256, 0, stream>>>(
        hbuf, CR, CR, mu1, rs1, ln1_g, ln1_b, wk, nullptr, kbuf);
    gemm_ln<<<dim3(CR / 64, MROWS / 64), 256, 0, stream>>>(
        hbuf, CR, CR, mu1, rs1, ln1_g, ln1_b, wv, nullptr, vbuf);
    // 7. out = h + attention(y)
    attn_kernel<<<dim3(NN / 64, BB * HEADS), 256, 0, stream>>>(qbuf, kbuf, vbuf, hbuf, out);
}

// Round 2
// 376.046 us; speedup vs baseline: 1.6439x; 1.6439x over previous
//
#include <hip/hip_runtime.h>
#include <math.h>

#define BB 8
#define NN 1024
#define DIM 768
#define HEADS 12
#define CR 384
#define HD 32
#define MROWS (BB*NN)   // 8192
#define EPS 1e-5f

typedef __attribute__((ext_vector_type(8))) __bf16 bf16x8;
typedef __attribute__((ext_vector_type(8))) unsigned short u16x8;
typedef __attribute__((ext_vector_type(4))) float f32x4;

__device__ inline unsigned short f2bf(float f) {
    unsigned int u = __float_as_uint(f);
    u += 0x7fffu + ((u >> 16) & 1u);   // RNE; inputs here are finite
    return (unsigned short)(u >> 16);
}

// ---------------- row stats: mean + rsqrt(var+eps) per row ----------------
__global__ __launch_bounds__(256) void row_stats(const float* __restrict__ A, int K,
                                                 float* __restrict__ mu, float* __restrict__ rs) {
    int row = blockIdx.x;
    const float* a = A + (size_t)row * K;
    float s = 0.f, ss = 0.f;
    for (int k = threadIdx.x; k < K; k += 256) {
        float v = a[k];
        s += v; ss += v * v;
    }
    for (int off = 32; off; off >>= 1) {
        s  += __shfl_down(s, off, 64);
        ss += __shfl_down(ss, off, 64);
    }
    __shared__ float redS[4], redSS[4];
    int lane = threadIdx.x & 63, wv = threadIdx.x >> 6;
    if (lane == 0) { redS[wv] = s; redSS[wv] = ss; }
    __syncthreads();
    if (threadIdx.x == 0) {
        float S = redS[0] + redS[1] + redS[2] + redS[3];
        float SS = redSS[0] + redSS[1] + redSS[2] + redSS[3];
        float m = S / K;
        float var = SS / K - m * m;
        mu[row] = m;
        rs[row] = rsqrtf(var + EPS);
    }
}

// ------------- C[m][n] = sum_k ((A[m][k]-mu[m])*rs[m]*g[k]+bt[k]) * W[n][k] + bias[n] -------------
// 64x64 tile, 256 threads, 4x4 microtile, K-step 16.  BF16OUT=true -> C is bf16 (ushort).
template <bool BF16OUT>
__global__ __launch_bounds__(256) void gemm_ln(
    const float* __restrict__ A, int K, int Nn,
    const float* __restrict__ mu, const float* __restrict__ rs,
    const float* __restrict__ g, const float* __restrict__ bt,
    const float* __restrict__ W, const float* __restrict__ bias,
    void* __restrict__ Cout)
{
    const int m0 = blockIdx.y * 64;
    const int n0 = blockIdx.x * 64;
    __shared__ float As[16][68];
    __shared__ float Bs[16][68];
    const int t = threadIdx.x;
    const int tx = t & 15, ty = t >> 4;
    const int lm = t >> 2;
    const int kq = (t & 3) * 4;
    float acc[4][4] = {};
    const float lmu = mu[m0 + lm], lrs = rs[m0 + lm];
    const float* arow = A + (size_t)(m0 + lm) * K;
    const float* wrow = W + (size_t)(n0 + lm) * K;
    for (int k0 = 0; k0 < K; k0 += 16) {
        float4 av = *(const float4*)(arow + k0 + kq);
        float4 wv = *(const float4*)(wrow + k0 + kq);
        float4 gv = *(const float4*)(g + k0 + kq);
        float4 bv = *(const float4*)(bt + k0 + kq);
        As[kq + 0][lm] = (av.x - lmu) * lrs * gv.x + bv.x;
        As[kq + 1][lm] = (av.y - lmu) * lrs * gv.y + bv.y;
        As[kq + 2][lm] = (av.z - lmu) * lrs * gv.z + bv.z;
        As[kq + 3][lm] = (av.w - lmu) * lrs * gv.w + bv.w;
        Bs[kq + 0][lm] = wv.x;
        Bs[kq + 1][lm] = wv.y;
        Bs[kq + 2][lm] = wv.z;
        Bs[kq + 3][lm] = wv.w;
        __syncthreads();
#pragma unroll
        for (int kk = 0; kk < 16; kk++) {
            float4 a4 = *(const float4*)&As[kk][ty * 4];
            float4 b4 = *(const float4*)&Bs[kk][tx * 4];
            float av4[4] = {a4.x, a4.y, a4.z, a4.w};
            float bv4[4] = {b4.x, b4.y, b4.z, b4.w};
#pragma unroll
            for (int i = 0; i < 4; i++)
#pragma unroll
                for (int j = 0; j < 4; j++)
                    acc[i][j] += av4[i] * bv4[j];
        }
        __syncthreads();
    }
    float4 biasv = make_float4(0.f, 0.f, 0.f, 0.f);
    if (bias) biasv = *(const float4*)(bias + n0 + tx * 4);
#pragma unroll
    for (int i = 0; i < 4; i++) {
        int row = m0 + ty * 4 + i;
        float o0 = acc[i][0] + biasv.x;
        float o1 = acc[i][1] + biasv.y;
        float o2 = acc[i][2] + biasv.z;
        float o3 = acc[i][3] + biasv.w;
        if constexpr (BF16OUT) {
            unsigned short* C16 = (unsigned short*)Cout;
            ushort4 o16 = make_ushort4(f2bf(o0), f2bf(o1), f2bf(o2), f2bf(o3));
            *(ushort4*)(C16 + (size_t)row * Nn + n0 + tx * 4) = o16;
        } else {
            float* C = (float*)Cout;
            *(float4*)(C + (size_t)row * Nn + n0 + tx * 4) = make_float4(o0, o1, o2, o3);
        }
    }
}

// ---------------- MFMA flash attention: block = (b, head, 64-q-tile), wave owns 16 q-rows ----------------
// A-layout (16x16x32): lane holds A[m=lane&15][k=quad*8+j].  B: lane holds B[k=quad*8+j][n=lane&15].
// C/D: lane holds D[row=quad*4+reg][col=lane&15]  (m89/m120-verified mappings).
__global__ __launch_bounds__(256) void attn_mfma(
    const unsigned short* __restrict__ q, const unsigned short* __restrict__ k,
    const unsigned short* __restrict__ v, const float* __restrict__ h,
    float* __restrict__ out)
{
    const int qt = blockIdx.x;           // 0..15
    const int bh = blockIdx.y;           // 0..95
    const int b = bh / HEADS, head = bh % HEADS;
    const int hc = head * HD;
    const int t = threadIdx.x;
    const int wave = t >> 6, lane = t & 63;
    const int l15 = lane & 15, quad = lane >> 4;
    const int q0 = qt * 64;

    __shared__ unsigned short Ks[64 * 40];      // [key][dim], pitch 40 (16B rows -> b128 frag reads)
    __shared__ unsigned short Vs[64 * 34];      // [key][dim], pitch 34 (scalar gather: 32-bank spread)
    __shared__ unsigned short Ps[4][16 * 72];   // per-wave P tile [q][key], pitch 72 (16B rows)

    // Q A-fragment (K dim = HD = 32 -> loaded exactly once)
    bf16x8 qa = *(const bf16x8*)(q + (size_t)(b * NN + q0 + wave * 16 + l15) * CR + hc + quad * 8);

    f32x4 o[2] = {{0.f,0.f,0.f,0.f},{0.f,0.f,0.f,0.f}};
    float m_run[4] = {-INFINITY, -INFINITY, -INFINITY, -INFINITY};
    float l_run[4] = {0.f, 0.f, 0.f, 0.f};
    const float scale = 0.17677669529663687f;   // 1/sqrt(32)

    const int rr = t >> 2, seg = t & 3;         // staging map: 4 threads per 64B row
    for (int kt = 0; kt < 16; kt++) {
        __syncthreads();                        // prev tile's Ks/Vs reads done
        {
            size_t grow = (size_t)(b * NN + kt * 64 + rr) * CR + hc + seg * 8;
            u16x8 kv = *(const u16x8*)(k + grow);
            u16x8 vv = *(const u16x8*)(v + grow);
            *(u16x8*)(&Ks[rr * 40 + seg * 8]) = kv;
            unsigned int* vd = (unsigned int*)&Vs[rr * 34 + seg * 8];  // 4B-aligned (pitch 34)
            union { u16x8 u; unsigned int w[4]; } cv; cv.u = vv;
            vd[0] = cv.w[0]; vd[1] = cv.w[1]; vd[2] = cv.w[2]; vd[3] = cv.w[3];
        }
        __syncthreads();

        // S tile: 16 q-rows x 64 keys = 4 MFMAs (K=32 in one shot)
        f32x4 s[4];
#pragma unroll
        for (int nt = 0; nt < 4; nt++) {
            bf16x8 kb = *(const bf16x8*)(&Ks[(nt * 16 + l15) * 40 + quad * 8]);
            f32x4 z = {0.f, 0.f, 0.f, 0.f};
            s[nt] = __builtin_amdgcn_mfma_f32_16x16x32_bf16(qa, kb, z, 0, 0, 0);
            s[nt] *= scale;
        }

        // online softmax, per q-row (row = quad*4+reg, spread over 16 lanes sharing quad)
        float alpha[4];
#pragma unroll
        for (int reg = 0; reg < 4; reg++) {
            float mloc = fmaxf(fmaxf(s[0][reg], s[1][reg]), fmaxf(s[2][reg], s[3][reg]));
#pragma unroll
            for (int off = 1; off < 16; off <<= 1)
                mloc = fmaxf(mloc, __shfl_xor(mloc, off, 64));
            float mnew = fmaxf(m_run[reg], mloc);
            alpha[reg] = __expf(m_run[reg] - mnew);   // first iter: exp(-inf)=0
            m_run[reg] = mnew;
            float rsum = 0.f;
#pragma unroll
            for (int nt = 0; nt < 4; nt++) {
                float e = __expf(s[nt][reg] - mnew);
                s[nt][reg] = e;
                rsum += e;
            }
#pragma unroll
            for (int off = 1; off < 16; off <<= 1)
                rsum += __shfl_xor(rsum, off, 64);
            l_run[reg] = l_run[reg] * alpha[reg] + rsum;
        }
#pragma unroll
        for (int reg = 0; reg < 4; reg++) { o[0][reg] *= alpha[reg]; o[1][reg] *= alpha[reg]; }

        // P (C-layout) -> per-wave LDS -> A-layout; no block barrier needed (wave-private region)
        unsigned short* Pw = Ps[wave];
#pragma unroll
        for (int nt = 0; nt < 4; nt++)
#pragma unroll
            for (int reg = 0; reg < 4; reg++)
                Pw[(quad * 4 + reg) * 72 + nt * 16 + l15] = f2bf(s[nt][reg]);

        // PV: P[16x64] @ V[64x32] = 2 k-steps x 2 n-tiles
#pragma unroll
        for (int kk = 0; kk < 2; kk++) {
            bf16x8 pa = *(const bf16x8*)(&Pw[l15 * 72 + kk * 32 + quad * 8]);
#pragma unroll
            for (int nt2 = 0; nt2 < 2; nt2++) {
                u16x8 vg;
#pragma unroll
                for (int j = 0; j < 8; j++)
                    vg[j] = Vs[(kk * 32 + quad * 8 + j) * 34 + nt2 * 16 + l15];
                o[nt2] = __builtin_amdgcn_mfma_f32_16x16x32_bf16(
                    pa, __builtin_bit_cast(bf16x8, vg), o[nt2], 0, 0, 0);
            }
        }
    }

    // epilogue: O/l + residual h, C-layout scatter (lanes 0..15 -> 64B contiguous)
#pragma unroll
    for (int nt2 = 0; nt2 < 2; nt2++)
#pragma unroll
        for (int reg = 0; reg < 4; reg++) {
            size_t idx = (size_t)(b * NN + q0 + wave * 16 + quad * 4 + reg) * CR
                       + hc + nt2 * 16 + l15;
            out[idx] = h[idx] + o[nt2][reg] / l_run[reg];
        }
}

extern "C" void kernel_launch(void* const* d_in, const int* in_sizes, int n_in,
                              void* d_out, int out_size, void* d_ws, size_t ws_size,
                              hipStream_t stream) {
    const float* x      = (const float*)d_in[0];
    const float* ln0_g  = (const float*)d_in[1];
    const float* ln0_b  = (const float*)d_in[2];
    const float* w_proj = (const float*)d_in[3];
    const float* b_proj = (const float*)d_in[4];
    const float* ln1_g  = (const float*)d_in[5];
    const float* ln1_b  = (const float*)d_in[6];
    const float* wq     = (const float*)d_in[7];
    const float* wk     = (const float*)d_in[8];
    const float* wv     = (const float*)d_in[9];
    float* out = (float*)d_out;

    float* ws  = (float*)d_ws;
    float* mu0 = ws;
    float* rs0 = ws + 8192;
    float* mu1 = ws + 16384;
    float* rs1 = ws + 24576;
    float* hbuf = ws + 32768;                         // 8192*384 f32
    unsigned short* qb = (unsigned short*)(hbuf + (size_t)MROWS * CR);
    unsigned short* kb = qb + (size_t)MROWS * CR;     // bf16 buffers
    unsigned short* vb = kb + (size_t)MROWS * CR;

    // 1. LN0 stats
    row_stats<<<MROWS, 256, 0, stream>>>(x, DIM, mu0, rs0);
    // 2. h = LN0(x) @ w_proj^T + b_proj   (f32)
    gemm_ln<false><<<dim3(CR / 64, MROWS / 64), 256, 0, stream>>>(
        x, DIM, CR, mu0, rs0, ln0_g, ln0_b, w_proj, b_proj, hbuf);
    // 3. LN1 stats
    row_stats<<<MROWS, 256, 0, stream>>>(hbuf, CR, mu1, rs1);
    // 4-6. q,k,v = LN1(h) @ w{q,k,v}^T    (bf16 out)
    gemm_ln<true><<<dim3(CR / 64, MROWS / 64), 256, 0, stream>>>(
        hbuf, CR, CR, mu1, rs1, ln1_g, ln1_b, wq, nullptr, qb);
    gemm_ln<true><<<dim3(CR / 64, MROWS / 64), 256, 0, stream>>>(
        hbuf, CR, CR, mu1, rs1, ln1_g, ln1_b, wk, nullptr, kb);
    gemm_ln<true><<<dim3(CR / 64, MROWS / 64), 256, 0, stream>>>(
        hbuf, CR, CR, mu1, rs1, ln1_g, ln1_b, wv, nullptr, vb);
    // 7. out = h + attention(softmax(QK^T/sqrt(d)) V)   (bf16 MFMA)
    attn_mfma<<<dim3(NN / 64, BB * HEADS), 256, 0, stream>>>(qb, kb, vb, hbuf, out);
}

// Round 3
// 175.809 us; speedup vs baseline: 3.5162x; 2.1389x over previous
//
#include <hip/hip_runtime.h>
#include <math.h>

#define BB 8
#define NN 1024
#define DIM 768
#define HEADS 12
#define CR 384
#define HD 32
#define MROWS (BB*NN)   // 8192
#define QKVP 1152       // concatenated q|k|v row pitch
#define EPS 1e-5f

typedef __attribute__((ext_vector_type(8))) __bf16 bf16x8;
typedef __attribute__((ext_vector_type(8))) unsigned short u16x8;
typedef __attribute__((ext_vector_type(4))) float f32x4;

__device__ __forceinline__ unsigned short f2bf(float f) {
    unsigned int u = __float_as_uint(f);
    u += 0x7fffu + ((u >> 16) & 1u);   // RNE; finite inputs only
    return (unsigned short)(u >> 16);
}

// async global->LDS, 16B per lane; lds dest = wave-uniform base + lane*16
__device__ __forceinline__ void async_cp16(const unsigned short* g, unsigned short* l) {
    __builtin_amdgcn_global_load_lds(
        (const __attribute__((address_space(1))) unsigned int*)g,
        (__attribute__((address_space(3))) unsigned int*)l, 16, 0, 0);
}

// ---------------- fused LN -> bf16: block per row ----------------
__global__ __launch_bounds__(256) void ln_bf16(
    const float* __restrict__ A, int K,
    const float* __restrict__ g, const float* __restrict__ bt,
    unsigned short* __restrict__ Y)
{
    const int row = blockIdx.x;
    const int t = threadIdx.x;
    const int nv = K >> 2;                 // float4 count (192 or 96)
    const float* a = A + (size_t)row * K;
    float4 val = make_float4(0.f, 0.f, 0.f, 0.f);
    float s = 0.f, ss = 0.f;
    if (t < nv) {
        val = ((const float4*)a)[t];
        s = val.x + val.y + val.z + val.w;
        ss = val.x * val.x + val.y * val.y + val.z * val.z + val.w * val.w;
    }
    for (int off = 32; off; off >>= 1) {
        s  += __shfl_down(s, off, 64);
        ss += __shfl_down(ss, off, 64);
    }
    __shared__ float rS[4], rSS[4];
    __shared__ float sh_mu, sh_rs;
    int lane = t & 63, w = t >> 6;
    if (lane == 0) { rS[w] = s; rSS[w] = ss; }
    __syncthreads();
    if (t == 0) {
        float S = rS[0] + rS[1] + rS[2] + rS[3];
        float SS = rSS[0] + rSS[1] + rSS[2] + rSS[3];
        float m = S / K;
        sh_mu = m;
        sh_rs = rsqrtf(SS / K - m * m + EPS);
    }
    __syncthreads();
    if (t < nv) {
        float m = sh_mu, r = sh_rs;
        float4 gv = ((const float4*)g)[t];
        float4 bv = ((const float4*)bt)[t];
        ushort4 o = make_ushort4(
            f2bf((val.x - m) * r * gv.x + bv.x),
            f2bf((val.y - m) * r * gv.y + bv.y),
            f2bf((val.z - m) * r * gv.z + bv.z),
            f2bf((val.w - m) * r * gv.w + bv.w));
        ((ushort4*)(Y + (size_t)row * K))[t] = o;
    }
}

// ---------------- cast weights f32->bf16: w_proj and concat(wq,wk,wv) ----------------
__global__ __launch_bounds__(256) void cast_weights(
    const float* __restrict__ wp, const float* __restrict__ wq,
    const float* __restrict__ wk, const float* __restrict__ wv,
    unsigned short* __restrict__ wpo, unsigned short* __restrict__ wqkvo)
{
    int i = blockIdx.x * 256 + threadIdx.x;    // float4 index; grid covers 184320
    const float* src; unsigned short* dst; int off;
    if (i < 73728) { src = wp; dst = wpo; off = i; }
    else {
        int j = i - 73728;
        int sel = j / 36864; off = j % 36864;
        src = sel == 0 ? wq : (sel == 1 ? wk : wv);
        dst = wqkvo + (size_t)sel * 147456;
    }
    float4 v = ((const float4*)src)[off];
    ushort4 o = make_ushort4(f2bf(v.x), f2bf(v.y), f2bf(v.z), f2bf(v.w));
    ((ushort4*)dst)[off] = o;
}

// ---------------- bf16 MFMA GEMM (m97 pattern): C[m][n] = sum_k A[m][k]*W[n][k] (+bias) ----------------
// tile 128 x BN, 256 threads, BK=32, global_load_lds width-16 staging, 16x16x32 MFMA.
template<int KD, int BN, bool BF16OUT>
__global__ __launch_bounds__(256) void gemm_mfma(
    const unsigned short* __restrict__ A,    // [M][KD] bf16
    const unsigned short* __restrict__ W,    // [Nn][KD] bf16
    const float* __restrict__ bias,          // [Nn] or null
    void* __restrict__ Cout, int Nn)
{
    constexpr int JT = BN / 32;              // b-frag / acc-col count (2 or 4)
    __shared__ unsigned short Asm[128 * 32];
    __shared__ unsigned short Bsm[BN * 32];
    const int t = threadIdx.x;
    const int wave = t >> 6, lane = t & 63;
    const int l15 = lane & 15, quad = lane >> 4;
    const int m0 = blockIdx.y * 128;
    const int n0 = blockIdx.x * BN;
    const int wm = (wave & 1) * 64, wn = (wave >> 1) * (BN / 2);

    const int srow = lane >> 2;              // 0..15
    const int skq  = (lane & 3) * 8;         // k-octet elem offset
    const unsigned short* gA0 = A + (size_t)(m0 + wave * 32 + srow) * KD + skq;
    const unsigned short* gB0 = W + (size_t)(n0 + wave * (BN / 4) + srow) * KD + skq;
    unsigned short* lA = Asm + wave * 1024;              // 32 rows * 32 elems
    unsigned short* lB = Bsm + wave * (BN * 8);          // BN/4 rows * 32 elems

    f32x4 acc[4][JT];
#pragma unroll
    for (int i = 0; i < 4; i++)
#pragma unroll
        for (int j = 0; j < JT; j++)
            acc[i][j] = (f32x4){0.f, 0.f, 0.f, 0.f};

    for (int k0 = 0; k0 < KD; k0 += 32) {
        __syncthreads();                     // prior-iter LDS reads done
        async_cp16(gA0 + k0, lA);
        async_cp16(gA0 + (size_t)16 * KD + k0, lA + 512);
        async_cp16(gB0 + k0, lB);
        if (BN == 128) async_cp16(gB0 + (size_t)16 * KD + k0, lB + 512);
        __syncthreads();                     // staging visible (vmcnt drained at barrier)

        bf16x8 af[4], bf[JT];
#pragma unroll
        for (int i = 0; i < 4; i++)
            af[i] = *(const bf16x8*)(Asm + (wm + i * 16 + l15) * 32 + quad * 8);
#pragma unroll
        for (int j = 0; j < JT; j++)
            bf[j] = *(const bf16x8*)(Bsm + (wn + j * 16 + l15) * 32 + quad * 8);
#pragma unroll
        for (int i = 0; i < 4; i++)
#pragma unroll
            for (int j = 0; j < JT; j++)
                acc[i][j] = __builtin_amdgcn_mfma_f32_16x16x32_bf16(af[i], bf[j], acc[i][j], 0, 0, 0);
    }

    // epilogue: D[row=quad*4+reg][col=l15] per 16x16 tile
    if constexpr (BF16OUT) {
        unsigned short* C = (unsigned short*)Cout;
#pragma unroll
        for (int i = 0; i < 4; i++)
#pragma unroll
            for (int j = 0; j < JT; j++)
#pragma unroll
                for (int reg = 0; reg < 4; reg++) {
                    int row = m0 + wm + i * 16 + quad * 4 + reg;
                    int col = n0 + wn + j * 16 + l15;
                    C[(size_t)row * Nn + col] = f2bf(acc[i][j][reg]);
                }
    } else {
        float* C = (float*)Cout;
        float bv[JT];
#pragma unroll
        for (int j = 0; j < JT; j++) bv[j] = bias[n0 + wn + j * 16 + l15];
#pragma unroll
        for (int i = 0; i < 4; i++)
#pragma unroll
            for (int j = 0; j < JT; j++)
#pragma unroll
                for (int reg = 0; reg < 4; reg++) {
                    int row = m0 + wm + i * 16 + quad * 4 + reg;
                    int col = n0 + wn + j * 16 + l15;
                    C[(size_t)row * Nn + col] = acc[i][j][reg] + bv[j];
                }
    }
}

// ---------------- MFMA flash attention, no-max softmax, V^T staging ----------------
__global__ __launch_bounds__(256) void attn_mfma(
    const unsigned short* __restrict__ qkv,   // [8192][1152] bf16: q|k|v
    const float* __restrict__ h, float* __restrict__ out)
{
    const int qt = blockIdx.x;                // 0..15
    const int bh = blockIdx.y;                // 0..95
    const int b = bh / HEADS, head = bh % HEADS;
    const int hc = head * HD;
    const int t = threadIdx.x;
    const int wave = t >> 6, lane = t & 63;
    const int l15 = lane & 15, quad = lane >> 4;
    const int q0 = qt * 64;

    __shared__ unsigned short Ks[64 * 40];     // [key][dim] pitch 40 (80B rows, 16B-aligned, 2-way free)
    __shared__ unsigned short Vt[32 * 72];     // [dim][key] pitch 72 (144B rows; b128 reads 2-way free)
    __shared__ unsigned short Ps[4][16 * 72];  // per-wave P [q][key] pitch 72

    // Q A-fragment (K=HD=32, loaded once); scale folded into exp argument
    bf16x8 qa = *(const bf16x8*)(qkv + (size_t)(b * NN + q0 + wave * 16 + l15) * QKVP + hc + quad * 8);

    f32x4 o[2] = {{0.f,0.f,0.f,0.f},{0.f,0.f,0.f,0.f}};
    float lpart[4] = {0.f, 0.f, 0.f, 0.f};
    const float scale = 0.17677669529663687f;  // 1/sqrt(32)

    // staging maps
    const int rr = t >> 2, seg = t & 3;        // K: 4 threads/key-row (coalesced 64B)
    const unsigned short* gK = qkv + (size_t)(b * NN + rr) * QKVP + CR + hc + seg * 8;
    const unsigned short* gV = qkv + (size_t)(b * NN + lane) * QKVP + 2 * CR + hc + wave * 8; // V: lane=key, wave=dim-octet

    for (int kt = 0; kt < 16; kt++) {
        __syncthreads();                       // prev tile's Ks/Vt reads done
        {
            u16x8 kv = *(const u16x8*)(gK + (size_t)kt * 64 * QKVP);
            *(u16x8*)(&Ks[rr * 40 + seg * 8]) = kv;
            u16x8 vv = *(const u16x8*)(gV + (size_t)kt * 64 * QKVP);
#pragma unroll
            for (int j = 0; j < 8; j++)        // transpose-scatter: banks (4j+key/2)%32 -> conflict-free
                Vt[(wave * 8 + j) * 72 + lane] = vv[j];
        }
        __syncthreads();

        // S = Q K^T : 4 MFMAs (16 q-rows x 64 keys, K=32)
        f32x4 s[4];
#pragma unroll
        for (int nt = 0; nt < 4; nt++) {
            bf16x8 kb = *(const bf16x8*)(&Ks[(nt * 16 + l15) * 40 + quad * 8]);
            f32x4 z = {0.f, 0.f, 0.f, 0.f};
            s[nt] = __builtin_amdgcn_mfma_f32_16x16x32_bf16(qa, kb, z, 0, 0, 0);
        }

        // no-max softmax numerator: P = exp(s*scale); l accumulated as per-lane partials
        unsigned short* Pw = Ps[wave];
#pragma unroll
        for (int nt = 0; nt < 4; nt++)
#pragma unroll
            for (int reg = 0; reg < 4; reg++) {
                float e = __expf(s[nt][reg] * scale);
                lpart[reg] += e;
                Pw[(quad * 4 + reg) * 72 + nt * 16 + l15] = f2bf(e);
            }

        // PV: P[16x64] @ V[64x32]; B-frags now ds_read_b128 from Vt
#pragma unroll
        for (int kk = 0; kk < 2; kk++) {
            bf16x8 pa = *(const bf16x8*)(&Pw[l15 * 72 + kk * 32 + quad * 8]);
#pragma unroll
            for (int nt2 = 0; nt2 < 2; nt2++) {
                bf16x8 vb = *(const bf16x8*)(&Vt[(nt2 * 16 + l15) * 72 + kk * 32 + quad * 8]);
                o[nt2] = __builtin_amdgcn_mfma_f32_16x16x32_bf16(pa, vb, o[nt2], 0, 0, 0);
            }
        }
    }

    // one deferred l reduction (16 lanes sharing quad)
#pragma unroll
    for (int reg = 0; reg < 4; reg++) {
        float l = lpart[reg];
#pragma unroll
        for (int off = 1; off < 16; off <<= 1) l += __shfl_xor(l, off, 64);
        lpart[reg] = 1.f / l;
    }

    // epilogue: out = h + O/l  (C-layout scatter)
#pragma unroll
    for (int nt2 = 0; nt2 < 2; nt2++)
#pragma unroll
        for (int reg = 0; reg < 4; reg++) {
            size_t idx = (size_t)(b * NN + q0 + wave * 16 + quad * 4 + reg) * CR
                       + hc + nt2 * 16 + l15;
            out[idx] = h[idx] + o[nt2][reg] * lpart[reg];
        }
}

extern "C" void kernel_launch(void* const* d_in, const int* in_sizes, int n_in,
                              void* d_out, int out_size, void* d_ws, size_t ws_size,
                              hipStream_t stream) {
    const float* x      = (const float*)d_in[0];
    const float* ln0_g  = (const float*)d_in[1];
    const float* ln0_b  = (const float*)d_in[2];
    const float* w_proj = (const float*)d_in[3];
    const float* b_proj = (const float*)d_in[4];
    const float* ln1_g  = (const float*)d_in[5];
    const float* ln1_b  = (const float*)d_in[6];
    const float* wq     = (const float*)d_in[7];
    const float* wk     = (const float*)d_in[8];
    const float* wv     = (const float*)d_in[9];
    float* out = (float*)d_out;

    // workspace layout (39.3 MB): qkv aliases a0 (a0 dead before qkv is written)
    char* base = (char*)d_ws;
    unsigned short* qkvb = (unsigned short*)base;               // 8192*1152*2 = 18,874,368
    unsigned short* a0   = (unsigned short*)base;               // 8192*768*2  = 12,582,912 (alias)
    float*          hbuf = (float*)(base + 18874368);           // 8192*384*4  = 12,582,912
    unsigned short* yb   = (unsigned short*)(base + 31457280);  // 8192*384*2  =  6,291,456
    unsigned short* wp   = (unsigned short*)(base + 37748736);  // 384*768*2   =    589,824
    unsigned short* wqkv = (unsigned short*)(base + 38338560);  // 1152*384*2  =    884,736

    // 1. a0 = bf16(LN0(x))
    ln_bf16<<<MROWS, 256, 0, stream>>>(x, DIM, ln0_g, ln0_b, a0);
    // 2. weight casts: wp = bf16(w_proj); wqkv = bf16([wq;wk;wv])
    cast_weights<<<720, 256, 0, stream>>>(w_proj, wq, wk, wv, wp, wqkv);
    // 3. h = a0 @ wp^T + b_proj   (f32 out, MFMA)
    gemm_mfma<DIM, 64, false><<<dim3(CR / 64, MROWS / 128), 256, 0, stream>>>(
        a0, wp, b_proj, hbuf, CR);
    // 4. y = bf16(LN1(h))
    ln_bf16<<<MROWS, 256, 0, stream>>>(hbuf, CR, ln1_g, ln1_b, yb);
    // 5. qkv = y @ wqkv^T   (bf16 out, MFMA)
    gemm_mfma<CR, 128, true><<<dim3(QKVP / 128, MROWS / 128), 256, 0, stream>>>(
        yb, wqkv, nullptr, qkvb, QKVP);
    // 6. out = h + attention
    attn_mfma<<<dim3(NN / 64, BB * HEADS), 256, 0, stream>>>(qkvb, hbuf, out);
}